// Round 5
// baseline (496.153 us; speedup 1.0000x reference)
//
#include <hip/hip_runtime.h>
#include <hip/hip_bf16.h>
#include <cstdint>
#include <cstddef>

// ---------------------------------------------------------------------------
// IPAttnProcessor: out = (softmax(QK^T)V + softmax(QKip^T)Vip) @ Wo + bo + residual
// B=8 SQ=4096 C=1280 CAD=2048 H=20 D=64 TXT=77 NT=4 IP_SCALE=1
// Big GEMMs: 256^2 tile, BK=64, dbuf-2 LDS, 4-phase/K-tile m201-style schedule
// (T2 swizzle + T3 phase interleave + T4 counted-flight staging + T5 setprio).
// Small GEMMs: m97 128^2 structure. Fused tiny-K attention (in-place on Q).
// ---------------------------------------------------------------------------

typedef __bf16 bf16_t;
typedef __bf16 bf16x8 __attribute__((ext_vector_type(8)));
typedef __bf16 bf16x4 __attribute__((ext_vector_type(4)));
typedef float  f32x4  __attribute__((ext_vector_type(4)));
typedef unsigned int u32x4 __attribute__((ext_vector_type(4)));

using as3_void  = __attribute__((address_space(3))) void;
using as1_cvoid = const __attribute__((address_space(1))) void;

#define TXT_ 77

__device__ __forceinline__ bf16x8 ld16(const void* p) {
  u32x4 v = *(const u32x4*)p;
  return __builtin_bit_cast(bf16x8, v);
}

// ---------------------------------------------------------------------------
// Big GEMM: C[M,N] = A[M,K] @ Bt[N,K]^T. 256x256 tile, BK=64, 512 thr (8 waves,
// 2M x 4N; per-wave out 128x64, acc[8][4]). LDS 128KB: A/B each 2 x 32KB dbuf.
// Per K-tile u (buf d=u&1), 4 phases (quadrant = m-half x k-half):
//   P: { ds_read frags | stage one half-tile of u+1 -> buf d^1 | s_barrier |
//        lgkmcnt(0)+sched_barrier | setprio(1) 16 MFMA setprio(0) | s_barrier }
// Stages: P1->A0, P2->A1, P3->B0, P4->B1 (each slot's last reader was tile u-1,
// done >=1 barrier before). vmcnt(0) once per tile at P4 (flights 1-3 phases).
// LDS rows 128B, phys_chunk = logical ^ (row&7); source pre-swizzled (lane>>3
// == row&7 within each 1KB global_load_lds unit).
// ---------------------------------------------------------------------------
template <int EPI>
__global__ __launch_bounds__(512, 2)
void gemm256(const bf16_t* __restrict__ A, const bf16_t* __restrict__ Bt,
             void* __restrict__ Cout, int ntn, int N, int K,
             const float* __restrict__ bias, const void* __restrict__ residual)
{
  __shared__ __align__(16) char smem[131072]; // A: [0,64K) 2x32KB; B: [64K,128K)
  const int tid = threadIdx.x, lane = tid & 63, wid = tid >> 6;
  const int wm = wid >> 2, wn = wid & 3;

  const int nwg = gridDim.x;
  int g = blockIdx.x;
  if ((nwg & 7) == 0) g = (blockIdx.x & 7) * (nwg >> 3) + (blockIdx.x >> 3);
  const long bm = (long)(g / ntn) * 256;
  const long bn = (long)(g % ntn) * 256;
  const int NTk = K >> 6;

  // staging lane geometry: 1KB unit = 8 rows x 128B; lane -> row r0+(lane>>3),
  // phys chunk lane&7 which must hold logical chunk (lane&7)^(lane>>3).
  const int srow = lane >> 3;
  const int scol = ((lane & 7) ^ srow) * 8;

  auto stage = [&](int mat, int h, int db, int u) {
    const bf16_t* gbase = mat ? Bt : A;
    const long rbase = (mat ? bn : bm) + h * 128 + wid * 8 + srow;
    char* lbase = smem + mat * 65536 + db * 32768 + (h * 128 + wid * 8) * 128;
#pragma unroll
    for (int j = 0; j < 2; ++j) {
      const bf16_t* gp = gbase + (rbase + j * 64) * (long)K + u * 64 + scol;
      __builtin_amdgcn_global_load_lds((as1_cvoid*)gp,
                                       (as3_void*)(lbase + j * 8192), 16, 0, 0);
    }
  };

  const int l15 = lane & 15, kq = lane >> 4;
  const int rswz = l15 & 7;

  auto ldA = [&](int d, int m, int ks) {
    return ld16(smem + d * 32768 + (wm * 128 + m * 16 + l15) * 128 +
                (((ks * 4 + kq) ^ rswz) << 4));
  };
  auto ldB = [&](int d, int n, int ks) {
    return ld16(smem + 65536 + d * 32768 + (wn * 64 + n * 16 + l15) * 128 +
                (((ks * 4 + kq) ^ rswz) << 4));
  };

  f32x4 acc[8][4] = {};
  bf16x8 afr[4], bfr[4];

  // prologue: tile 0 -> buf 0 (8 loads/wave), drain, barrier
  stage(0, 0, 0, 0); stage(0, 1, 0, 0); stage(1, 0, 0, 0); stage(1, 1, 0, 0);
  asm volatile("s_waitcnt vmcnt(0)" ::: "memory");
  __builtin_amdgcn_s_barrier();

  for (int u = 0; u < NTk; ++u) {
    const int d = u & 1;
    const bool pf = (u + 1 < NTk);

    // ---- P1: frags (A m0-3, B all; ks=0), stage A0(u+1), MFMA acc[0-3] ----
#pragma unroll
    for (int m = 0; m < 4; ++m) afr[m] = ldA(d, m, 0);
#pragma unroll
    for (int n = 0; n < 4; ++n) bfr[n] = ldB(d, n, 0);
    if (pf) stage(0, 0, d ^ 1, u + 1);
    __builtin_amdgcn_s_barrier();
    asm volatile("s_waitcnt lgkmcnt(0)" ::: "memory");
    __builtin_amdgcn_sched_barrier(0);
    __builtin_amdgcn_s_setprio(1);
#pragma unroll
    for (int m = 0; m < 4; ++m)
#pragma unroll
      for (int n = 0; n < 4; ++n)
        acc[m][n] = __builtin_amdgcn_mfma_f32_16x16x32_bf16(afr[m], bfr[n], acc[m][n], 0, 0, 0);
    __builtin_amdgcn_s_setprio(0);
    __builtin_amdgcn_s_barrier();

    // ---- P2: frags (A m4-7 ks0), stage A1(u+1), MFMA acc[4-7] ----
#pragma unroll
    for (int m = 0; m < 4; ++m) afr[m] = ldA(d, m + 4, 0);
    if (pf) stage(0, 1, d ^ 1, u + 1);
    __builtin_amdgcn_s_barrier();
    asm volatile("s_waitcnt lgkmcnt(0)" ::: "memory");
    __builtin_amdgcn_sched_barrier(0);
    __builtin_amdgcn_s_setprio(1);
#pragma unroll
    for (int m = 0; m < 4; ++m)
#pragma unroll
      for (int n = 0; n < 4; ++n)
        acc[m + 4][n] = __builtin_amdgcn_mfma_f32_16x16x32_bf16(afr[m], bfr[n], acc[m + 4][n], 0, 0, 0);
    __builtin_amdgcn_s_setprio(0);
    __builtin_amdgcn_s_barrier();

    // ---- P3: frags (A m0-3, B all; ks=1), stage B0(u+1), MFMA acc[0-3] ----
#pragma unroll
    for (int m = 0; m < 4; ++m) afr[m] = ldA(d, m, 1);
#pragma unroll
    for (int n = 0; n < 4; ++n) bfr[n] = ldB(d, n, 1);
    if (pf) stage(1, 0, d ^ 1, u + 1);
    __builtin_amdgcn_s_barrier();
    asm volatile("s_waitcnt lgkmcnt(0)" ::: "memory");
    __builtin_amdgcn_sched_barrier(0);
    __builtin_amdgcn_s_setprio(1);
#pragma unroll
    for (int m = 0; m < 4; ++m)
#pragma unroll
      for (int n = 0; n < 4; ++n)
        acc[m][n] = __builtin_amdgcn_mfma_f32_16x16x32_bf16(afr[m], bfr[n], acc[m][n], 0, 0, 0);
    __builtin_amdgcn_s_setprio(0);
    __builtin_amdgcn_s_barrier();

    // ---- P4: frags (A m4-7 ks1), stage B1(u+1), MFMA acc[4-7], drain ----
#pragma unroll
    for (int m = 0; m < 4; ++m) afr[m] = ldA(d, m + 4, 1);
    if (pf) stage(1, 1, d ^ 1, u + 1);
    __builtin_amdgcn_s_barrier();
    asm volatile("s_waitcnt lgkmcnt(0)" ::: "memory");
    __builtin_amdgcn_sched_barrier(0);
    __builtin_amdgcn_s_setprio(1);
#pragma unroll
    for (int m = 0; m < 4; ++m)
#pragma unroll
      for (int n = 0; n < 4; ++n)
        acc[m + 4][n] = __builtin_amdgcn_mfma_f32_16x16x32_bf16(afr[m], bfr[n], acc[m + 4][n], 0, 0, 0);
    __builtin_amdgcn_s_setprio(0);
    asm volatile("s_waitcnt vmcnt(0)" ::: "memory");
    __builtin_amdgcn_s_barrier();
  }

  const int orow0 = (lane >> 4) << 2;
#pragma unroll
  for (int m = 0; m < 8; ++m) {
#pragma unroll
    for (int n = 0; n < 4; ++n) {
      const long col = bn + wn * 64 + n * 16 + l15;
#pragma unroll
      for (int r = 0; r < 4; ++r) {
        const long row = bm + wm * 128 + m * 16 + orow0 + r;
        if constexpr (EPI == 0) {
          ((bf16_t*)Cout)[row * N + col] = (bf16_t)acc[m][n][r];
        } else {
          ((float*)Cout)[row * N + col] =
              acc[m][n][r] + bias[col] +
              (float)((const bf16_t*)residual)[row * N + col];
        }
      }
    }
  }
}

// ---------------------------------------------------------------------------
// Small GEMM (m97 128^2 structure), used for K/V projections.
// ---------------------------------------------------------------------------
__global__ __launch_bounds__(256, 4)
void gemm_bt(const bf16_t* __restrict__ A, const bf16_t* __restrict__ Bt,
             bf16_t* __restrict__ Cout, int ntn, int N, int K)
{
  __shared__ __align__(16) char smem[2][16384];
  const int tid  = threadIdx.x;
  const int lane = tid & 63;
  const int wid  = tid >> 6;
  const int wm = wid >> 1, wn = wid & 1;

  const int g = blockIdx.x;
  const long bm = (long)(g / ntn) * 128;
  const long bn = (long)(g % ntn) * 128;

  f32x4 acc[4][4] = {};

  const int srow = lane >> 2;
  const int skb  = (lane & 3) ^ (((lane >> 2) ^ (lane >> 4)) & 3);
  const int NT = K >> 5;

  auto stage = [&](int buf, int kt) {
    const int k0 = kt << 5;
#pragma unroll
    for (int cc = 0; cc < 2; ++cc) {
      const int c = wid + cc * 4;
      const bf16_t* ga = A + (bm + c * 16 + srow) * (long)K + (k0 + skb * 8);
      __builtin_amdgcn_global_load_lds((as1_cvoid*)ga,
                                       (as3_void*)(&smem[buf][c * 1024]), 16, 0, 0);
      const bf16_t* gb = Bt + (bn + c * 16 + srow) * (long)K + (k0 + skb * 8);
      __builtin_amdgcn_global_load_lds((as1_cvoid*)gb,
                                       (as3_void*)(&smem[buf][8192 + c * 1024]), 16, 0, 0);
    }
  };

  const int rkb    = (((lane >> 4) ^ (lane & 3) ^ ((lane >> 2) & 3)) & 3) << 4;
  const int rrow_a = wm * 64 + (lane & 15);
  const int rrow_b = wn * 64 + (lane & 15);

  stage(0, 0);
  int cur = 0;
  for (int t = 0; t < NT; ++t) {
    __syncthreads();
    if (t + 1 < NT) stage(cur ^ 1, t + 1);
    const char* sa = smem[cur];
    const char* sb = smem[cur] + 8192;
    bf16x8 af[4], bfv[4];
#pragma unroll
    for (int m = 0; m < 4; ++m)
      af[m] = ld16(sa + (rrow_a + m * 16) * 64 + rkb);
#pragma unroll
    for (int n = 0; n < 4; ++n)
      bfv[n] = ld16(sb + (rrow_b + n * 16) * 64 + rkb);
#pragma unroll
    for (int m = 0; m < 4; ++m)
#pragma unroll
      for (int n = 0; n < 4; ++n)
        acc[m][n] = __builtin_amdgcn_mfma_f32_16x16x32_bf16(af[m], bfv[n], acc[m][n], 0, 0, 0);
    cur ^= 1;
  }

  const int orow0 = wm * 64 + ((lane >> 4) << 2);
  const int ocol0 = wn * 64 + (lane & 15);
#pragma unroll
  for (int m = 0; m < 4; ++m)
#pragma unroll
    for (int n = 0; n < 4; ++n) {
      const long col = bn + ocol0 + n * 16;
#pragma unroll
      for (int r = 0; r < 4; ++r)
        Cout[(bm + orow0 + m * 16 + r) * (long)N + col] = (bf16_t)acc[m][n][r];
    }
}

// ---------------------------------------------------------------------------
// Fused attention (unchanged; writes in-place over Q).
// ---------------------------------------------------------------------------
__global__ __launch_bounds__(256, 3)
void attn_fused(const bf16_t* __restrict__ q, const bf16_t* __restrict__ kvt,
                const bf16_t* __restrict__ kvip, bf16_t* __restrict__ outp)
{
  __shared__ __align__(16) bf16_t K_lds[80 * 64];
  __shared__ __align__(16) bf16_t Kip_lds[16 * 64];
  __shared__ __align__(16) bf16_t Vt_lds[64 * 128];
  __shared__ __align__(16) bf16_t P_lds[4][16 * 128];

  const int tid = threadIdx.x, lane = tid & 63, wid = tid >> 6;
  const int h = blockIdx.y, b = blockIdx.z;
  const int kvcol = h << 6;

  for (int idx = tid; idx < 640; idx += 256) {
    const int j = idx >> 3, c = idx & 7;
    bf16x8 v = {};
    if (j < TXT_) v = ld16(kvt + (long)(b * 80 + j) * 2560 + kvcol + c * 8);
    *(bf16x8*)((char*)K_lds + j * 128 + ((c ^ (j & 7)) << 4)) = v;
  }
  if (tid < 128) {
    const int j = tid >> 3, c = tid & 7;
    bf16x8 v = {};
    if (j < 4) v = ld16(kvip + (long)(b * 4 + j) * 2560 + kvcol + c * 8);
    *(bf16x8*)((char*)Kip_lds + j * 128 + ((c ^ (j & 7)) << 4)) = v;
  }
  for (int idx = tid; idx < 1024; idx += 256) {
    const int key = idx >> 3, c = idx & 7;
    bf16x8 v = {};
    if (key < TXT_)
      v = ld16(kvt + (long)(b * 80 + key) * 2560 + 1280 + kvcol + c * 8);
    else if (key >= 96 && key < 100)
      v = ld16(kvip + (long)(b * 4 + key - 96) * 2560 + 1280 + kvcol + c * 8);
#pragma unroll
    for (int e = 0; e < 8; ++e) {
      const int d = c * 8 + e;
      *(bf16_t*)((char*)Vt_lds + d * 256 + ((key * 2) ^ ((d & 7) << 4))) = v[e];
    }
  }
  for (int idx = tid; idx < 1024; idx += 256)
    *(bf16x8*)((char*)P_lds + idx * 16) = (bf16x8){};
  __syncthreads();

  const int l15 = lane & 15, hi = lane >> 4;
  const int dblk = hi << 3;
  const int prow0 = hi << 2;
  const float scale = 0.125f;
  char* const pw = (char*)P_lds[wid];

  const long qrow0 = (long)b * 4096 + ((long)blockIdx.x << 8) + (wid << 6);
  bf16x8 qf[4][2];
#pragma unroll
  for (int ms = 0; ms < 4; ++ms) {
    const bf16_t* qp = q + (qrow0 + ms * 16 + l15) * 1280 + kvcol;
    qf[ms][0] = ld16(qp + dblk);
    qf[ms][1] = ld16(qp + 32 + dblk);
  }

#pragma unroll
  for (int ms = 0; ms < 4; ++ms) {
    f32x4 sc[5];
#pragma unroll
    for (int t = 0; t < 5; ++t) {
      const int j = (t << 4) + l15;
      const bf16x8 k0 = ld16((char*)K_lds + j * 128 + ((hi ^ (j & 7)) << 4));
      const bf16x8 k1 = ld16((char*)K_lds + j * 128 + (((4 + hi) ^ (j & 7)) << 4));
      f32x4 z = {0.f, 0.f, 0.f, 0.f};
      z = __builtin_amdgcn_mfma_f32_16x16x32_bf16(qf[ms][0], k0, z, 0, 0, 0);
      z = __builtin_amdgcn_mfma_f32_16x16x32_bf16(qf[ms][1], k1, z, 0, 0, 0);
      sc[t] = z;
    }
#pragma unroll
    for (int t = 0; t < 5; ++t) {
      const bool valid = ((t << 4) + l15) < TXT_;
#pragma unroll
      for (int r = 0; r < 4; ++r)
        sc[t][r] = valid ? sc[t][r] * scale : -1e30f;
    }

#pragma unroll
    for (int r = 0; r < 4; ++r) {
      float m = sc[0][r];
#pragma unroll
      for (int t = 1; t < 5; ++t) m = fmaxf(m, sc[t][r]);
      m = fmaxf(m, __shfl_xor(m, 1));
      m = fmaxf(m, __shfl_xor(m, 2));
      m = fmaxf(m, __shfl_xor(m, 4));
      m = fmaxf(m, __shfl_xor(m, 8));
      float l = 0.f;
#pragma unroll
      for (int t = 0; t < 5; ++t) { const float p = __expf(sc[t][r] - m); sc[t][r] = p; l += p; }
      l += __shfl_xor(l, 1);
      l += __shfl_xor(l, 2);
      l += __shfl_xor(l, 4);
      l += __shfl_xor(l, 8);
      const float inv = 1.f / l;
      const int row = prow0 + r;
#pragma unroll
      for (int t = 0; t < 5; ++t)
        *(bf16_t*)(pw + row * 256 + ((((t << 4) + l15) * 2) ^ ((row & 7) << 4))) =
            (bf16_t)(sc[t][r] * inv);
    }

    {
      const bf16x8 ki0 = ld16((char*)Kip_lds + l15 * 128 + ((hi ^ (l15 & 7)) << 4));
      const bf16x8 ki1 = ld16((char*)Kip_lds + l15 * 128 + (((4 + hi) ^ (l15 & 7)) << 4));
      f32x4 z = {0.f, 0.f, 0.f, 0.f};
      z = __builtin_amdgcn_mfma_f32_16x16x32_bf16(qf[ms][0], ki0, z, 0, 0, 0);
      z = __builtin_amdgcn_mfma_f32_16x16x32_bf16(qf[ms][1], ki1, z, 0, 0, 0);
      const bool vip = l15 < 4;
#pragma unroll
      for (int r = 0; r < 4; ++r) {
        const float s = vip ? z[r] * scale : -1e30f;
        float m = s;
        m = fmaxf(m, __shfl_xor(m, 1));
        m = fmaxf(m, __shfl_xor(m, 2));
        m = fmaxf(m, __shfl_xor(m, 4));
        m = fmaxf(m, __shfl_xor(m, 8));
        const float p = __expf(s - m);
        float l = p;
        l += __shfl_xor(l, 1);
        l += __shfl_xor(l, 2);
        l += __shfl_xor(l, 4);
        l += __shfl_xor(l, 8);
        const int row = prow0 + r;
        *(bf16_t*)(pw + row * 256 + (((96 + l15) * 2) ^ ((row & 7) << 4))) =
            (bf16_t)(p * (1.f / l));
      }
    }

    f32x4 o[4] = {};
#pragma unroll
    for (int s = 0; s < 4; ++s) {
      const bf16x8 pa =
          ld16(pw + l15 * 256 + ((((s << 2) + hi) << 4) ^ ((l15 & 7) << 4)));
#pragma unroll
      for (int n = 0; n < 4; ++n) {
        const int d = (n << 4) + l15;
        const bf16x8 vb =
            ld16((char*)Vt_lds + d * 256 + ((((s << 2) + hi) << 4) ^ ((d & 7) << 4)));
        o[n] = __builtin_amdgcn_mfma_f32_16x16x32_bf16(pa, vb, o[n], 0, 0, 0);
      }
    }

    const long orow = qrow0 + ms * 16 + prow0;
#pragma unroll
    for (int n = 0; n < 4; ++n)
#pragma unroll
      for (int r = 0; r < 4; ++r)
        outp[(orow + r) * 1280 + kvcol + (n << 4) + l15] = (bf16_t)o[n][r];
  }
}

// ---------------------------------------------------------------------------
// Utility kernels
// ---------------------------------------------------------------------------
__global__ void cvt_bf16(const float* __restrict__ in, bf16_t* __restrict__ out, long n)
{
  const long i = ((long)blockIdx.x * 256 + threadIdx.x) * 4;
  if (i >= n) return;
  const float4 v = *(const float4*)(in + i);
  bf16x4 r;
  r[0] = (bf16_t)v.x; r[1] = (bf16_t)v.y; r[2] = (bf16_t)v.z; r[3] = (bf16_t)v.w;
  *(bf16x4*)(out + i) = r;
}

__global__ void transpose_cvt(const float* __restrict__ in, bf16_t* __restrict__ out,
                              int K, int N, int ostride)
{
  __shared__ float tile[32][33];
  const int k0 = blockIdx.x * 32, n0 = blockIdx.y * 32;
  for (int i = threadIdx.y; i < 32; i += 8)
    tile[i][threadIdx.x] = in[(long)(k0 + i) * N + n0 + threadIdx.x];
  __syncthreads();
  for (int i = threadIdx.y; i < 32; i += 8)
    out[(long)(n0 + i) * ostride + k0 + threadIdx.x] = (bf16_t)tile[threadIdx.x][i];
}

__global__ void pack_enc(const float* __restrict__ enc, bf16_t* __restrict__ a_txt,
                         bf16_t* __restrict__ a_ip)
{
  const long t4 = ((long)blockIdx.x * 256 + threadIdx.x) * 4;
  const long NTXT = 640L * 2048;
  bf16x4 r;
  r[0] = r[1] = r[2] = r[3] = (bf16_t)0.f;
  if (t4 < NTXT) {
    const int row = (int)(t4 >> 11), col = (int)(t4 & 2047);
    const int b = row / 80, j = row - b * 80;
    if (j < TXT_) {
      const float4 v = *(const float4*)(enc + (((long)(b * 81 + j)) << 11) + col);
      r[0] = (bf16_t)v.x; r[1] = (bf16_t)v.y; r[2] = (bf16_t)v.z; r[3] = (bf16_t)v.w;
    }
    *(bf16x4*)(a_txt + t4) = r;
  } else {
    const long u = t4 - NTXT;
    const int row = (int)(u >> 11), col = (int)(u & 2047);
    if (row < 32) {
      const int b = row >> 2, j = row & 3;
      const float4 v = *(const float4*)(enc + (((long)(b * 81 + TXT_ + j)) << 11) + col);
      r[0] = (bf16_t)v.x; r[1] = (bf16_t)v.y; r[2] = (bf16_t)v.z; r[3] = (bf16_t)v.w;
    }
    *(bf16x4*)(a_ip + u) = r;
  }
}

// ---------------------------------------------------------------------------
extern "C" void kernel_launch(void* const* d_in, const int* in_sizes, int n_in,
                              void* d_out, int out_size, void* d_ws, size_t ws_size,
                              hipStream_t stream)
{
  (void)in_sizes; (void)n_in; (void)out_size; (void)ws_size;
  const float* hs  = (const float*)d_in[0];
  const float* enc = (const float*)d_in[1];
  const float* Wq  = (const float*)d_in[2];
  const float* Wk  = (const float*)d_in[3];
  const float* Wv  = (const float*)d_in[4];
  const float* Wki = (const float*)d_in[5];
  const float* Wvi = (const float*)d_in[6];
  const float* Wo  = (const float*)d_in[7];
  const float* bo  = (const float*)d_in[8];

  char* ws = (char*)d_ws;
  size_t off = 0;
  auto alloc = [&](size_t bytes) {
    char* p = ws + off;
    off += (bytes + 255) & ~(size_t)255;
    return p;
  };
  bf16_t* buf1   = (bf16_t*)alloc(83886080);  // hs_bf16 (A of GEMM1 + residual of GEMM2)
  bf16_t* qb     = (bf16_t*)alloc(83886080);  // Q (32768 x 1280), attn in-place
  bf16_t* Wq_t   = (bf16_t*)alloc(3276800);
  bf16_t* Wo_t   = (bf16_t*)alloc(3276800);
  bf16_t* Wkv_t  = (bf16_t*)alloc(10485760);
  bf16_t* Wip_t  = (bf16_t*)alloc(10485760);
  bf16_t* a_txt  = (bf16_t*)alloc(2621440);
  bf16_t* a_ip   = (bf16_t*)alloc(524288);
  bf16_t* kv_txt = (bf16_t*)alloc(3276800);
  bf16_t* kv_ip  = (bf16_t*)alloc(655360);

  const dim3 tb(32, 8);
  cvt_bf16<<<40960, 256, 0, stream>>>(hs, buf1, 41943040L);
  transpose_cvt<<<dim3(40, 40), tb, 0, stream>>>(Wq, Wq_t, 1280, 1280, 1280);
  transpose_cvt<<<dim3(40, 40), tb, 0, stream>>>(Wo, Wo_t, 1280, 1280, 1280);
  transpose_cvt<<<dim3(64, 40), tb, 0, stream>>>(Wk, Wkv_t, 2048, 1280, 2048);
  transpose_cvt<<<dim3(64, 40), tb, 0, stream>>>(Wv, Wkv_t + (long)1280 * 2048, 2048, 1280, 2048);
  transpose_cvt<<<dim3(64, 40), tb, 0, stream>>>(Wki, Wip_t, 2048, 1280, 2048);
  transpose_cvt<<<dim3(64, 40), tb, 0, stream>>>(Wvi, Wip_t + (long)1280 * 2048, 2048, 1280, 2048);
  pack_enc<<<1536, 256, 0, stream>>>(enc, a_txt, a_ip);

  // Q = hs_bf16 @ Wq   (256^2 4-phase pipeline, XCD-chunked N-fast swizzle)
  gemm256<0><<<640, 512, 0, stream>>>(buf1, Wq_t, qb, 5, 1280, 1280,
                                      nullptr, nullptr);
  // K|V = txt @ [Wk|Wv]
  gemm_bt<<<100, 256, 0, stream>>>(a_txt, Wkv_t, kv_txt, 20, 2560, 2048);
  // Kip|Vip = ip @ [Wk_ip|Wv_ip]
  gemm_bt<<<20, 256, 0, stream>>>(a_ip, Wip_t, kv_ip, 20, 2560, 2048);

  // fused dual-softmax attention, in-place on qb
  attn_fused<<<dim3(16, 20, 8), 256, 0, stream>>>(qb, kv_txt, kv_ip, qb);

  // out = attn @ Wo + bo + residual(bf16)
  gemm256<2><<<640, 512, 0, stream>>>(qb, Wo_t, d_out, 5, 1280, 1280,
                                      bo, buf1);
}